// Round 13
// baseline (181.307 us; speedup 1.0000x reference)
//
#include <hip/hip_runtime.h>
#include <hip/hip_bf16.h>

#define T_SEQ 4096
#define NB 4
#define CEMB 2048
#define HS 128

typedef __attribute__((ext_vector_type(8))) short bf16x8;
typedef __attribute__((ext_vector_type(4))) float f32x4;
typedef __attribute__((ext_vector_type(16))) float f32x16;

__device__ inline short f2bf(float f) {
    union { float f; unsigned u; } v; v.f = f;
    unsigned r = v.u + 0x7FFFu + ((v.u >> 16) & 1u);   // RNE
    return (short)(r >> 16);
}

__device__ inline unsigned pk2(float lo, float hi) {
    unsigned r;
    asm("v_cvt_pk_bf16_f32 %0, %1, %2" : "=v"(r) : "v"(lo), "v"(hi));
    return r;
}

__device__ inline void gld16(const void* gsrc, void* lds) {
    __builtin_amdgcn_global_load_lds(
        (const __attribute__((address_space(1))) unsigned*)gsrc,
        (__attribute__((address_space(3))) unsigned*)lds, 16, 0, 0);
}

// ---------------- kernel 1: W -> B-fragment-packed bf16 ----------------------
// Wt[mat][k16][c32][lane][j]: flat idx -> j=idx&7, lane=(idx>>3)&63,
// c32=(idx>>9)&3, k16=(idx>>11)&127, mat=idx>>18.
// Element: col = c32*32 + (lane&31), k = k16*16 + (lane>>5)*8 + j.
// A wave's B-fragment load is then ONE contiguous 1KB global read.
__global__ __launch_bounds__(256) void wt_kernel(
    const float* __restrict__ Wq, const float* __restrict__ Wk,
    const float* __restrict__ Wv, short* __restrict__ Wt) {
    int idx = blockIdx.x * 256 + threadIdx.x;   // 3*128*4*64*8 = 786432
    int j    = idx & 7;
    int lane = (idx >> 3) & 63;
    int c32  = (idx >> 9) & 3;
    int k16  = (idx >> 11) & 127;
    int mat  = idx >> 18;
    int col  = c32 * 32 + (lane & 31);
    int k    = k16 * 16 + ((lane >> 5) << 3) + j;
    const float* W = (mat == 0) ? Wq : (mat == 1) ? Wk : Wv;
    Wt[idx] = f2bf(W[k * HS + col]);
}

// ---------------- kernel 2: q/k/v projection v4 (no LDS, no barriers) --------
// 32x32x16 MFMA. Block = 4 waves = 64 rows x 128 cols of ONE matrix;
// wave w: rows (w>>1)*32, cols (w&1)*64. W fragments read directly from the
// fragment-packed Wt (1KB coalesced L2 hits); x depth-1 register prefetch.
// grid 768 XCD-chunked. q pre-scaled by log2(e)/sqrt(2048).
__global__ __launch_bounds__(256, 3) void proj_kernel(
    const float* __restrict__ x, const short* __restrict__ Wt,
    short* __restrict__ qg, short* __restrict__ kg, short* __restrict__ vtg) {
    const int tid = threadIdx.x;
    const int w   = tid >> 6;
    const int l   = tid & 63;
    const int c31 = l & 31;
    const int hi  = l >> 5;

    const int bid = blockIdx.x;
    const int wk  = (bid & 7) * 96 + (bid >> 3);   // same-XCD chunking
    const int mat = wk % 3;
    const int m0  = (wk / 3) * 64;

    const int rgbase = (w >> 1) << 5;    // 0 / 32
    const int wc     = (w & 1) << 6;     // 0 / 64
    const int c32b   = wc >> 5;          // 0 / 2

    const short* Wm = Wt + (long)mat * 262144;
    const float* xrow = x + (long)(m0 + rgbase + c31) * CEMB + hi * 8;

    f32x16 acc0, acc1;
    #pragma unroll
    for (int i = 0; i < 16; i++) { acc0[i] = 0.f; acc1[i] = 0.f; }

    float4 xc[4][2], xn[4][2];
    #pragma unroll
    for (int kc = 0; kc < 4; kc++) {
        xc[kc][0] = *reinterpret_cast<const float4*>(xrow + kc * 16);
        xc[kc][1] = *reinterpret_cast<const float4*>(xrow + kc * 16 + 4);
    }

    #pragma unroll 2
    for (int s = 0; s < 32; ++s) {
        // ---- depth-1 x prefetch ----
        if (s < 31) {
            const float* xp = xrow + (s + 1) * 64;
            #pragma unroll
            for (int kc = 0; kc < 4; kc++) {
                xn[kc][0] = *reinterpret_cast<const float4*>(xp + kc * 16);
                xn[kc][1] = *reinterpret_cast<const float4*>(xp + kc * 16 + 4);
            }
        }

        #pragma unroll
        for (int kc = 0; kc < 4; kc++) {
            // A fragment: row = c31, k = kc16*16 + hi*8 + j
            union { unsigned u[4]; bf16x8 v; } A;
            A.u[0] = pk2(xc[kc][0].x, xc[kc][0].y);
            A.u[1] = pk2(xc[kc][0].z, xc[kc][0].w);
            A.u[2] = pk2(xc[kc][1].x, xc[kc][1].y);
            A.u[3] = pk2(xc[kc][1].z, xc[kc][1].w);

            const long k16 = (long)(s * 4 + kc);
            bf16x8 w0 = *reinterpret_cast<const bf16x8*>(
                Wm + (k16 * 4 + c32b) * 512 + l * 8);
            bf16x8 w1 = *reinterpret_cast<const bf16x8*>(
                Wm + (k16 * 4 + c32b + 1) * 512 + l * 8);

            acc0 = __builtin_amdgcn_mfma_f32_32x32x16_bf16(A.v, w0, acc0, 0, 0, 0);
            acc1 = __builtin_amdgcn_mfma_f32_32x32x16_bf16(A.v, w1, acc1, 0, 0, 0);
        }

        #pragma unroll
        for (int kc = 0; kc < 4; kc++) { xc[kc][0] = xn[kc][0]; xc[kc][1] = xn[kc][1]; }
    }

    // ---- store (D: col = c31, row = (r&3) + 8*(r>>2) + 4*hi) ----
    if (mat == 0) {
        const float scale = 0.0318793851f;  // log2(e)/sqrt(2048) folded into q
        #pragma unroll
        for (int r = 0; r < 16; r++) {
            int grow = m0 + rgbase + (r & 3) + 8 * (r >> 2) + 4 * hi;
            qg[(long)grow * HS + wc + c31]      = f2bf(acc0[r] * scale);
            qg[(long)grow * HS + wc + 32 + c31] = f2bf(acc1[r] * scale);
        }
    } else if (mat == 1) {
        // K image: 8192 shorts per 64-row tile; byte = (r64*256 + d*2) ^ ((r64&7)<<4)
        #pragma unroll
        for (int r = 0; r < 16; r++) {
            int grow = m0 + rgbase + (r & 3) + 8 * (r >> 2) + 4 * hi;
            long tile = grow >> 6;
            int r64  = grow & 63;
            int d0   = wc + c31;
            int b0   = (r64 * 256 + d0 * 2) ^ ((r64 & 7) << 4);
            int b1   = (r64 * 256 + (d0 + 32) * 2) ^ ((r64 & 7) << 4);
            kg[tile * 8192 + (b0 >> 1)] = f2bf(acc0[r]);
            kg[tile * 8192 + (b1 >> 1)] = f2bf(acc1[r]);
        }
    } else {
        #pragma unroll
        for (int r = 0; r < 16; r++) {
            int grow = m0 + rgbase + (r & 3) + 8 * (r >> 2) + 4 * hi;
            int b2 = grow >> 12;
            int tl = grow & 4095;
            int d0 = wc + c31;
            vtg[(long)b2 * (HS * T_SEQ) + (long)d0 * T_SEQ + tl]        = f2bf(acc0[r]);
            vtg[(long)b2 * (HS * T_SEQ) + (long)(d0 + 32) * T_SEQ + tl] = f2bf(acc1[r]);
        }
    }
}

// ---------------- kernel 3: flash attention v5 (unchanged from round 11) -----
__global__ __launch_bounds__(512, 2) void attn_kernel(
    const short* __restrict__ qg, const short* __restrict__ kg,
    const short* __restrict__ vtg, float* __restrict__ out) {
    __shared__ __align__(16) char pool[131072];   // 8 waves x 16KB
    __shared__ float Lm[8][32];
    __shared__ float Ll[8][32];

    const int tid = threadIdx.x;
    const int w   = tid >> 6;      // wave 0..7 = kv-split index
    const int l   = tid & 63;
    const int c31 = l & 31;
    const int hi  = l >> 5;
    const int hi4 = hi << 2;
    const int hi8 = hi << 3;

    const int bid = blockIdx.x;
    const int xcd = bid & 7;
    const int idx = bid >> 3;                        // 0..31
    const int b   = xcd >> 1;                        // batch pinned to XCD pair
    const int qtA = 127 - ((idx << 1) | (xcd & 1));  // 64..127

    const short* kbimg = kg + (long)b * 64 * 8192;   // 64 K-tile images per batch
    const short* vb    = vtg + (long)b * HS * T_SEQ;

    short* Kw = (short*)(pool + (w << 14));          // wave-private 16KB

#define STAGEK(TILE) do {                                                  \
        const short* gp_ = kbimg + (long)(TILE) * 8192 + l * 8;            \
        _Pragma("unroll")                                                  \
        for (int i = 0; i < 16; i++)                                       \
            gld16(gp_ + i * 512, Kw + i * 512 + l * 8);                    \
    } while (0)

    const int swz = (c31 & 7) << 4;
    const int rbA = c31 * 256;
    const int rbB = (32 + c31) * 256;

    #pragma unroll 1
    for (int ph = 0; ph < 2; ++ph) {
        const int qt   = ph ? (127 - qtA) : qtA;
        const int q0   = qt * 32;
        const int qrow = q0 + c31;
        const int ntk  = (qt >> 1) + 1;

        bf16x8 qf[8];
        #pragma unroll
        for (int kc = 0; kc < 8; kc++)
            qf[kc] = *reinterpret_cast<const bf16x8*>(
                &qg[(long)(b * T_SEQ + qrow) * HS + kc * 16 + hi8]);

        f32x16 accO[4];
        #pragma unroll
        for (int nb = 0; nb < 4; nb++)
            #pragma unroll
            for (int i = 0; i < 16; i++) accO[nb][i] = 0.f;
        float mrow = -__builtin_inff();
        float lsum = 0.f;

        if (w < ntk) STAGEK(w);

        #pragma unroll 1
        for (int t = w; t < ntk; t += 8) {
            const int kv0 = t * 64;

            asm volatile("s_waitcnt vmcnt(0)" ::: "memory");

            bf16x8 vfA[2][4];
            #pragma unroll
            for (int kc = 0; kc < 2; kc++)
                #pragma unroll
                for (int nb = 0; nb < 4; nb++)
                    vfA[kc][nb] = *reinterpret_cast<const bf16x8*>(
                        &vb[(long)(nb * 32 + c31) * T_SEQ + kv0 + kc * 16 + hi8]);

            f32x16 SA, SB;
            #pragma unroll
            for (int i = 0; i < 16; i++) { SA[i] = 0.f; SB[i] = 0.f; }
            __builtin_amdgcn_s_setprio(1);
            #pragma unroll
            for (int kc = 0; kc < 8; kc++) {
                const int cb = kc * 32 + hi * 16;
                bf16x8 ka = *reinterpret_cast<const bf16x8*>(
                    (const char*)Kw + ((rbA + cb) ^ swz));
                bf16x8 kb2 = *reinterpret_cast<const bf16x8*>(
                    (const char*)Kw + ((rbB + cb) ^ swz));
                SA = __builtin_amdgcn_mfma_f32_32x32x16_bf16(ka,  qf[kc], SA, 0, 0, 0);
                SB = __builtin_amdgcn_mfma_f32_32x32x16_bf16(kb2, qf[kc], SB, 0, 0, 0);
            }
            __builtin_amdgcn_s_setprio(0);

            if (t + 8 < ntk) STAGEK(t + 8);

            float pA[16], pB[16];
            #pragma unroll
            for (int r = 0; r < 16; r++) { pA[r] = SA[r]; pB[r] = SB[r]; }

            if (kv0 + 63 > q0) {
                #pragma unroll
                for (int r = 0; r < 16; r++) {
                    int kr = kv0 + (r & 3) + 8 * (r >> 2) + hi4;
                    pA[r] = (kr > qrow)      ? -__builtin_inff() : pA[r];
                    pB[r] = (kr + 32 > qrow) ? -__builtin_inff() : pB[r];
                }
            }

            float t16[16];
            #pragma unroll
            for (int r = 0; r < 16; r++) t16[r] = fmaxf(pA[r], pB[r]);
            #pragma unroll
            for (int s2 = 8; s2 >= 1; s2 >>= 1)
                #pragma unroll
                for (int r = 0; r < 8; r++)
                    if (r < s2) t16[r] = fmaxf(t16[r], t16[r + s2]);
            float mt = fmaxf(t16[0], __shfl_xor(t16[0], 32));

            if (__any(mt > mrow)) {
                float mnew = fmaxf(mrow, mt);
                float fac  = exp2f(mrow - mnew);
                lsum *= fac;
                #pragma unroll
                for (int nb = 0; nb < 4; nb++)
                    #pragma unroll
                    for (int i = 0; i < 16; i++) accO[nb][i] *= fac;
                mrow = mnew;
            }

            bf16x8 vfB[2][4];
            #pragma unroll
            for (int kc = 0; kc < 2; kc++)
                #pragma unroll
                for (int nb = 0; nb < 4; nb++)
                    vfB[kc][nb] = *reinterpret_cast<const bf16x8*>(
                        &vb[(long)(nb * 32 + c31) * T_SEQ + kv0 + (kc + 2) * 16 + hi8]);

            #pragma unroll
            for (int r = 0; r < 16; r++) {
                pA[r] = exp2f(pA[r] - mrow);
                pB[r] = exp2f(pB[r] - mrow);
            }
            float s16[16];
            #pragma unroll
            for (int r = 0; r < 16; r++) s16[r] = pA[r] + pB[r];
            #pragma unroll
            for (int s2 = 8; s2 >= 1; s2 >>= 1)
                #pragma unroll
                for (int r = 0; r < 8; r++)
                    if (r < s2) s16[r] += s16[r + s2];
            lsum += s16[0] + __shfl_xor(s16[0], 32);

            bf16x8 pf[4];
            #pragma unroll
            for (int kc = 0; kc < 4; kc++) {
                const int V0 = 2 * kc, V1 = 2 * kc + 1;
                const int r0 = ((V0 >> 2) << 4) | ((V0 & 3) << 2);
                const int r1 = ((V1 >> 2) << 4) | ((V1 & 3) << 2);
#define PSEL(i) ((i) < 16 ? pA[(i) & 15] : pB[(i) & 15])
                unsigned a0 = pk2(PSEL(r0 + 0), PSEL(r0 + 1));
                unsigned a1 = pk2(PSEL(r0 + 2), PSEL(r0 + 3));
                unsigned b0 = pk2(PSEL(r1 + 0), PSEL(r1 + 1));
                unsigned b1 = pk2(PSEL(r1 + 2), PSEL(r1 + 3));
#undef PSEL
                unsigned k0 = hi ? b0 : a0, k1 = hi ? b1 : a1;
                unsigned s0 = hi ? a0 : b0, s1 = hi ? a1 : b1;
                unsigned g0 = (unsigned)__shfl_xor((int)s0, 32);
                unsigned g1 = (unsigned)__shfl_xor((int)s1, 32);
                union { unsigned u[4]; bf16x8 v; } U;
                U.u[0] = hi ? g0 : k0;
                U.u[1] = hi ? g1 : k1;
                U.u[2] = hi ? k0 : g0;
                U.u[3] = hi ? k1 : g1;
                pf[kc] = U.v;
            }

            __builtin_amdgcn_s_setprio(1);
            #pragma unroll
            for (int nb = 0; nb < 4; nb++)
                accO[nb] = __builtin_amdgcn_mfma_f32_32x32x16_bf16(pf[0], vfA[0][nb], accO[nb], 0, 0, 0);
            #pragma unroll
            for (int nb = 0; nb < 4; nb++)
                accO[nb] = __builtin_amdgcn_mfma_f32_32x32x16_bf16(pf[1], vfA[1][nb], accO[nb], 0, 0, 0);
            #pragma unroll
            for (int nb = 0; nb < 4; nb++)
                accO[nb] = __builtin_amdgcn_mfma_f32_32x32x16_bf16(pf[2], vfB[0][nb], accO[nb], 0, 0, 0);
            #pragma unroll
            for (int nb = 0; nb < 4; nb++)
                accO[nb] = __builtin_amdgcn_mfma_f32_32x32x16_bf16(pf[3], vfB[1][nb], accO[nb], 0, 0, 0);
            __builtin_amdgcn_s_setprio(0);
        }

        __syncthreads();   // all waves done reading their K slices this phase
        {
            float* LaccW = (float*)(pool + (w << 14));   // [32][128]
            #pragma unroll
            for (int nb = 0; nb < 4; nb++)
                #pragma unroll
                for (int r = 0; r < 16; r++)
                    LaccW[((r & 3) + 8 * (r >> 2) + hi4) * 128 + nb * 32 + c31] = accO[nb][r];
            if (l < 32) { Lm[w][c31] = mrow; Ll[w][c31] = lsum; }
        }
        __syncthreads();

        {
            const int row = tid >> 4;
            const int c0  = (tid & 15) * 8;
            float mv[8], lv[8];
            #pragma unroll
            for (int p2 = 0; p2 < 8; p2++) { mv[p2] = Lm[p2][row]; lv[p2] = Ll[p2][row]; }
            float ms = mv[0];
            #pragma unroll
            for (int p2 = 1; p2 < 8; p2++) ms = fmaxf(ms, mv[p2]);
            float fv[8];
            float L = 0.f;
            #pragma unroll
            for (int p2 = 0; p2 < 8; p2++) { fv[p2] = exp2f(mv[p2] - ms); L += lv[p2] * fv[p2]; }
            float inv = 1.0f / L;
            float* op = &out[((long)b * T_SEQ + q0 + row) * HS + c0];
            #pragma unroll
            for (int j = 0; j < 8; j++) {
                float o = 0.f;
                #pragma unroll
                for (int p2 = 0; p2 < 8; p2++)
                    o += ((const float*)(pool + (p2 << 14)))[row * 128 + c0 + j] * fv[p2];
                op[j] = o * inv;
            }
        }
        __syncthreads();   // merge reads done before next phase restages K
    }
#undef STAGEK
}

// ---------------- launch ------------------------------------------------------
extern "C" void kernel_launch(void* const* d_in, const int* in_sizes, int n_in,
                              void* d_out, int out_size, void* d_ws, size_t ws_size,
                              hipStream_t stream) {
    const float* x  = (const float*)d_in[0];
    const float* Wk = (const float*)d_in[1];
    const float* Wq = (const float*)d_in[2];
    const float* Wv = (const float*)d_in[3];
    float* out = (float*)d_out;

    char* ws = (char*)d_ws;
    short* Wt  = (short*)ws;                                  // 1.5 MB (fragment-packed)
    short* qg  = (short*)(ws + 1572864);                      // 4 MB
    short* kg  = (short*)(ws + 1572864 + 4194304);            // 4 MB (K tile images)
    short* vtg = (short*)(ws + 1572864 + 8388608);            // 4 MB

    wt_kernel  <<<3072, 256, 0, stream>>>(Wq, Wk, Wv, Wt);
    proj_kernel<<<768,  256, 0, stream>>>(x, Wt, qg, kg, vtg);
    attn_kernel<<<256,  512, 0, stream>>>(qg, kg, vtg, out);
}

// Round 14
// 131.756 us; speedup vs baseline: 1.3761x; 1.3761x over previous
//
#include <hip/hip_runtime.h>
#include <hip/hip_bf16.h>

#define T_SEQ 4096
#define NB 4
#define CEMB 2048
#define HS 128

typedef __attribute__((ext_vector_type(8))) short bf16x8;
typedef __attribute__((ext_vector_type(4))) float f32x4;
typedef __attribute__((ext_vector_type(16))) float f32x16;

__device__ inline short f2bf(float f) {
    union { float f; unsigned u; } v; v.f = f;
    unsigned r = v.u + 0x7FFFu + ((v.u >> 16) & 1u);   // RNE
    return (short)(r >> 16);
}

__device__ inline unsigned pk2(float lo, float hi) {
    unsigned r;
    asm("v_cvt_pk_bf16_f32 %0, %1, %2" : "=v"(r) : "v"(lo), "v"(hi));
    return r;
}

__device__ inline void gld16(const void* gsrc, void* lds) {
    __builtin_amdgcn_global_load_lds(
        (const __attribute__((address_space(1))) unsigned*)gsrc,
        (__attribute__((address_space(3))) unsigned*)lds, 16, 0, 0);
}

// ---------------- kernel 1: W -> pre-swizzled bf16 LDS-image panels ----------
__global__ __launch_bounds__(256) void wt_kernel(
    const float* __restrict__ Wq, const float* __restrict__ Wk,
    const float* __restrict__ Wv, short* __restrict__ Wt) {
    int d = blockIdx.x * 256 + threadIdx.x;     // 3*32*8192 = 786432
    int mat = d >> 18;
    int rm  = d & 262143;
    int s   = rm >> 13;                         // panel 0..31
    int e   = rm & 8191;
    int p   = e * 2;
    int n   = p >> 7;
    int lin = p ^ ((n & 7) << 4);
    int kk  = (lin & 127) >> 1;
    int k   = s * 64 + kk;
    const float* W = (mat == 0) ? Wq : (mat == 1) ? Wk : Wv;
    Wt[d] = f2bf(W[k * HS + n]);
}

// ---------------- kernel 2: q/k/v projection v5 ------------------------------
// R11 3-buffer LDS pipeline with DEEPER x cover: per step issue order is
// STAGE_W(s+2) THEN LOADX(s+3); wait vmcnt(12) drains exactly {x(s), W(s)}.
// x window = 3 step-bodies (~1200cy > HBM 900cy), W window = 2.
// grid 768 XCD-chunked; q pre-scaled by log2(e)/sqrt(2048); k stored as
// pre-swizzled 64-row tile images; v transposed [B][128][T].
__global__ __launch_bounds__(256, 3) void proj_kernel(
    const float* __restrict__ x, const short* __restrict__ Wt,
    short* __restrict__ qg, short* __restrict__ kg, short* __restrict__ vtg) {
    __shared__ short Wlds[3][8192];   // 3 x 16KB panels

    const int tid = threadIdx.x;
    const int w   = tid >> 6;
    const int l   = tid & 63;
    const int lg  = l >> 4;
    const int lr  = l & 15;

    const int bid = blockIdx.x;
    const int wk  = (bid & 7) * 96 + (bid >> 3);   // same-XCD chunking
    const int mat = wk % 3;
    const int m0  = (wk / 3) * 64;

    const short* Wp = Wt + (long)mat * 262144;

    f32x4 acc[8];
    #pragma unroll
    for (int b = 0; b < 8; b++) acc[b] = (f32x4){0.f, 0.f, 0.f, 0.f};

    const float* xrow = x + (long)(m0 + w * 16 + lr) * CEMB;
    const int sw = (lr & 7) << 4;

    float4 xs[4][4];   // 4-slot rotation, fully unrolled -> constant indices

#define STAGE(S, B) do {                                                   \
        const short* gp_ = Wp + (long)(S) * 8192 + (long)(w * 4) * 512 + l * 8; \
        gld16(gp_,        &Wlds[B][(w * 4 + 0) * 512]);                    \
        gld16(gp_ + 512,  &Wlds[B][(w * 4 + 1) * 512]);                    \
        gld16(gp_ + 1024, &Wlds[B][(w * 4 + 2) * 512]);                    \
        gld16(gp_ + 1536, &Wlds[B][(w * 4 + 3) * 512]);                    \
    } while (0)

#define LOADX(S, XB) do {                                                  \
        const float* xn_ = xrow + (S) * 64;                                \
        xs[XB][0] = *reinterpret_cast<const float4*>(xn_ + lg * 8);        \
        xs[XB][1] = *reinterpret_cast<const float4*>(xn_ + lg * 8 + 4);    \
        xs[XB][2] = *reinterpret_cast<const float4*>(xn_ + 32 + lg * 8);   \
        xs[XB][3] = *reinterpret_cast<const float4*>(xn_ + 32 + lg * 8 + 4);\
    } while (0)

#define BODY(S, XB) do {                                                   \
        bf16x8 a0, a1;                                                     \
        a0[0] = f2bf(xs[XB][0].x); a0[1] = f2bf(xs[XB][0].y);              \
        a0[2] = f2bf(xs[XB][0].z); a0[3] = f2bf(xs[XB][0].w);              \
        a0[4] = f2bf(xs[XB][1].x); a0[5] = f2bf(xs[XB][1].y);              \
        a0[6] = f2bf(xs[XB][1].z); a0[7] = f2bf(xs[XB][1].w);              \
        a1[0] = f2bf(xs[XB][2].x); a1[1] = f2bf(xs[XB][2].y);              \
        a1[2] = f2bf(xs[XB][2].z); a1[3] = f2bf(xs[XB][2].w);              \
        a1[4] = f2bf(xs[XB][3].x); a1[5] = f2bf(xs[XB][3].y);              \
        a1[6] = f2bf(xs[XB][3].z); a1[7] = f2bf(xs[XB][3].w);              \
        const char* lbase_ = (const char*)&Wlds[(S) % 3][0];               \
        _Pragma("unroll")                                                  \
        for (int nt = 0; nt < 8; nt++) {                                   \
            int off_ = (((nt * 16 + lr) * 128 + lg * 16)) ^ sw;            \
            bf16x8 bfr_ = *reinterpret_cast<const bf16x8*>(lbase_ + off_); \
            acc[nt] = __builtin_amdgcn_mfma_f32_16x16x32_bf16(             \
                a0, bfr_, acc[nt], 0, 0, 0);                               \
        }                                                                  \
        _Pragma("unroll")                                                  \
        for (int nt = 0; nt < 8; nt++) {                                   \
            int off_ = (((nt * 16 + lr) * 128 + lg * 16 + 64)) ^ sw;       \
            bf16x8 bfr_ = *reinterpret_cast<const bf16x8*>(lbase_ + off_); \
            acc[nt] = __builtin_amdgcn_mfma_f32_16x16x32_bf16(             \
                a1, bfr_, acc[nt], 0, 0, 0);                               \
        }                                                                  \
    } while (0)

    // prologue order: W0, x0, W1, x1, x2  (20 outstanding)
    STAGE(0, 0);
    LOADX(0, 0);
    STAGE(1, 1);
    LOADX(1, 1);
    LOADX(2, 2);

    // steps 0..29: uniform vmcnt(12) drains exactly {x(s), W(s)}
    #pragma unroll
    for (int s = 0; s < 30; ++s) {
        asm volatile("s_waitcnt vmcnt(12) lgkmcnt(0)\n\ts_barrier" ::: "memory");
        STAGE(s + 2, (s + 2) % 3);          // W first...
        if (s + 3 < 32) LOADX(s + 3, (s + 3) & 3);   // ...then x (deeper slot)
        BODY(s, s & 3);
    }
    // step 30: drain {x30, W30}, leave {x31, W31}
    {
        asm volatile("s_waitcnt vmcnt(8) lgkmcnt(0)\n\ts_barrier" ::: "memory");
        BODY(30, 30 & 3);
    }
    // step 31: drain everything
    {
        asm volatile("s_waitcnt vmcnt(0) lgkmcnt(0)\n\ts_barrier" ::: "memory");
        BODY(31, 31 & 3);
    }

#undef BODY
#undef LOADX
#undef STAGE

    if (mat == 0) {
        const float scale = 0.0318793851f;  // log2(e) / sqrt(2048), folded into q
        #pragma unroll
        for (int nt = 0; nt < 8; nt++)
            #pragma unroll
            for (int r = 0; r < 4; r++) {
                int row = m0 + w * 16 + lg * 4 + r;
                qg[(long)row * HS + nt * 16 + lr] = f2bf(acc[nt][r] * scale);
            }
    } else if (mat == 1) {
        // K image: 8192 shorts/tile, byte = (r64*256 + d*2) ^ ((r64&7)<<4)
        short* kt = kg + ((long)(m0 >> 6)) * 8192;
        #pragma unroll
        for (int nt = 0; nt < 8; nt++)
            #pragma unroll
            for (int r = 0; r < 4; r++) {
                int r64  = w * 16 + lg * 4 + r;
                int byte = (r64 * 256 + (nt * 16 + lr) * 2) ^ ((r64 & 7) << 4);
                kt[byte >> 1] = f2bf(acc[nt][r]);
            }
    } else {
        #pragma unroll
        for (int nt = 0; nt < 8; nt++)
            #pragma unroll
            for (int r = 0; r < 4; r++) {
                int row = m0 + w * 16 + lg * 4 + r;
                int b   = row >> 12;
                int tl  = row & 4095;
                vtg[(long)b * (HS * T_SEQ) + (long)(nt * 16 + lr) * T_SEQ + tl]
                    = f2bf(acc[nt][r]);
            }
    }
}

// ---------------- kernel 3: flash attention v5 (unchanged from round 11) -----
__global__ __launch_bounds__(512, 2) void attn_kernel(
    const short* __restrict__ qg, const short* __restrict__ kg,
    const short* __restrict__ vtg, float* __restrict__ out) {
    __shared__ __align__(16) char pool[131072];   // 8 waves x 16KB
    __shared__ float Lm[8][32];
    __shared__ float Ll[8][32];

    const int tid = threadIdx.x;
    const int w   = tid >> 6;      // wave 0..7 = kv-split index
    const int l   = tid & 63;
    const int c31 = l & 31;
    const int hi  = l >> 5;
    const int hi4 = hi << 2;
    const int hi8 = hi << 3;

    const int bid = blockIdx.x;
    const int xcd = bid & 7;
    const int idx = bid >> 3;                        // 0..31
    const int b   = xcd >> 1;                        // batch pinned to XCD pair
    const int qtA = 127 - ((idx << 1) | (xcd & 1));  // 64..127

    const short* kbimg = kg + (long)b * 64 * 8192;   // 64 K-tile images per batch
    const short* vb    = vtg + (long)b * HS * T_SEQ;

    short* Kw = (short*)(pool + (w << 14));          // wave-private 16KB

#define STAGEK(TILE) do {                                                  \
        const short* gp_ = kbimg + (long)(TILE) * 8192 + l * 8;            \
        _Pragma("unroll")                                                  \
        for (int i = 0; i < 16; i++)                                       \
            gld16(gp_ + i * 512, Kw + i * 512 + l * 8);                    \
    } while (0)

    const int swz = (c31 & 7) << 4;
    const int rbA = c31 * 256;
    const int rbB = (32 + c31) * 256;

    #pragma unroll 1
    for (int ph = 0; ph < 2; ++ph) {
        const int qt   = ph ? (127 - qtA) : qtA;
        const int q0   = qt * 32;
        const int qrow = q0 + c31;
        const int ntk  = (qt >> 1) + 1;

        bf16x8 qf[8];
        #pragma unroll
        for (int kc = 0; kc < 8; kc++)
            qf[kc] = *reinterpret_cast<const bf16x8*>(
                &qg[(long)(b * T_SEQ + qrow) * HS + kc * 16 + hi8]);

        f32x16 accO[4];
        #pragma unroll
        for (int nb = 0; nb < 4; nb++)
            #pragma unroll
            for (int i = 0; i < 16; i++) accO[nb][i] = 0.f;
        float mrow = -__builtin_inff();
        float lsum = 0.f;

        if (w < ntk) STAGEK(w);

        #pragma unroll 1
        for (int t = w; t < ntk; t += 8) {
            const int kv0 = t * 64;

            asm volatile("s_waitcnt vmcnt(0)" ::: "memory");

            bf16x8 vfA[2][4];
            #pragma unroll
            for (int kc = 0; kc < 2; kc++)
                #pragma unroll
                for (int nb = 0; nb < 4; nb++)
                    vfA[kc][nb] = *reinterpret_cast<const bf16x8*>(
                        &vb[(long)(nb * 32 + c31) * T_SEQ + kv0 + kc * 16 + hi8]);

            f32x16 SA, SB;
            #pragma unroll
            for (int i = 0; i < 16; i++) { SA[i] = 0.f; SB[i] = 0.f; }
            __builtin_amdgcn_s_setprio(1);
            #pragma unroll
            for (int kc = 0; kc < 8; kc++) {
                const int cb = kc * 32 + hi * 16;
                bf16x8 ka = *reinterpret_cast<const bf16x8*>(
                    (const char*)Kw + ((rbA + cb) ^ swz));
                bf16x8 kb2 = *reinterpret_cast<const bf16x8*>(
                    (const char*)Kw + ((rbB + cb) ^ swz));
                SA = __builtin_amdgcn_mfma_f32_32x32x16_bf16(ka,  qf[kc], SA, 0, 0, 0);
                SB = __builtin_amdgcn_mfma_f32_32x32x16_bf16(kb2, qf[kc], SB, 0, 0, 0);
            }
            __builtin_amdgcn_s_setprio(0);

            if (t + 8 < ntk) STAGEK(t + 8);

            float pA[16], pB[16];
            #pragma unroll
            for (int r = 0; r < 16; r++) { pA[r] = SA[r]; pB[r] = SB[r]; }

            if (kv0 + 63 > q0) {
                #pragma unroll
                for (int r = 0; r < 16; r++) {
                    int kr = kv0 + (r & 3) + 8 * (r >> 2) + hi4;
                    pA[r] = (kr > qrow)      ? -__builtin_inff() : pA[r];
                    pB[r] = (kr + 32 > qrow) ? -__builtin_inff() : pB[r];
                }
            }

            float t16[16];
            #pragma unroll
            for (int r = 0; r < 16; r++) t16[r] = fmaxf(pA[r], pB[r]);
            #pragma unroll
            for (int s2 = 8; s2 >= 1; s2 >>= 1)
                #pragma unroll
                for (int r = 0; r < 8; r++)
                    if (r < s2) t16[r] = fmaxf(t16[r], t16[r + s2]);
            float mt = fmaxf(t16[0], __shfl_xor(t16[0], 32));

            if (__any(mt > mrow)) {
                float mnew = fmaxf(mrow, mt);
                float fac  = exp2f(mrow - mnew);
                lsum *= fac;
                #pragma unroll
                for (int nb = 0; nb < 4; nb++)
                    #pragma unroll
                    for (int i = 0; i < 16; i++) accO[nb][i] *= fac;
                mrow = mnew;
            }

            bf16x8 vfB[2][4];
            #pragma unroll
            for (int kc = 0; kc < 2; kc++)
                #pragma unroll
                for (int nb = 0; nb < 4; nb++)
                    vfB[kc][nb] = *reinterpret_cast<const bf16x8*>(
                        &vb[(long)(nb * 32 + c31) * T_SEQ + kv0 + (kc + 2) * 16 + hi8]);

            #pragma unroll
            for (int r = 0; r < 16; r++) {
                pA[r] = exp2f(pA[r] - mrow);
                pB[r] = exp2f(pB[r] - mrow);
            }
            float s16[16];
            #pragma unroll
            for (int r = 0; r < 16; r++) s16[r] = pA[r] + pB[r];
            #pragma unroll
            for (int s2 = 8; s2 >= 1; s2 >>= 1)
                #pragma unroll
                for (int r = 0; r < 8; r++)
                    if (r < s2) s16[r] += s16[r + s2];
            lsum += s16[0] + __shfl_xor(s16[0], 32);

            bf16x8 pf[4];
            #pragma unroll
            for (int kc = 0; kc < 4; kc++) {
                const int V0 = 2 * kc, V1 = 2 * kc + 1;
                const int r0 = ((V0 >> 2) << 4) | ((V0 & 3) << 2);
                const int r1 = ((V1 >> 2) << 4) | ((V1 & 3) << 2);
#define PSEL(i) ((i) < 16 ? pA[(i) & 15] : pB[(i) & 15])
                unsigned a0 = pk2(PSEL(r0 + 0), PSEL(r0 + 1));
                unsigned a1 = pk2(PSEL(r0 + 2), PSEL(r0 + 3));
                unsigned b0 = pk2(PSEL(r1 + 0), PSEL(r1 + 1));
                unsigned b1 = pk2(PSEL(r1 + 2), PSEL(r1 + 3));
#undef PSEL
                unsigned k0 = hi ? b0 : a0, k1 = hi ? b1 : a1;
                unsigned s0 = hi ? a0 : b0, s1 = hi ? a1 : b1;
                unsigned g0 = (unsigned)__shfl_xor((int)s0, 32);
                unsigned g1 = (unsigned)__shfl_xor((int)s1, 32);
                union { unsigned u[4]; bf16x8 v; } U;
                U.u[0] = hi ? g0 : k0;
                U.u[1] = hi ? g1 : k1;
                U.u[2] = hi ? k0 : g0;
                U.u[3] = hi ? k1 : g1;
                pf[kc] = U.v;
            }

            __builtin_amdgcn_s_setprio(1);
            #pragma unroll
            for (int nb = 0; nb < 4; nb++)
                accO[nb] = __builtin_amdgcn_mfma_f32_32x32x16_bf16(pf[0], vfA[0][nb], accO[nb], 0, 0, 0);
            #pragma unroll
            for (int nb = 0; nb < 4; nb++)
                accO[nb] = __builtin_amdgcn_mfma_f32_32x32x16_bf16(pf[1], vfA[1][nb], accO[nb], 0, 0, 0);
            #pragma unroll
            for (int nb = 0; nb < 4; nb++)
                accO[nb] = __builtin_amdgcn_mfma_f32_32x32x16_bf16(pf[2], vfB[0][nb], accO[nb], 0, 0, 0);
            #pragma unroll
            for (int nb = 0; nb < 4; nb++)
                accO[nb] = __builtin_amdgcn_mfma_f32_32x32x16_bf16(pf[3], vfB[1][nb], accO[nb], 0, 0, 0);
            __builtin_amdgcn_s_setprio(0);
        }

        __syncthreads();   // all waves done reading their K slices this phase
        {
            float* LaccW = (float*)(pool + (w << 14));   // [32][128]
            #pragma unroll
            for (int nb = 0; nb < 4; nb++)
                #pragma unroll
                for (int r = 0; r < 16; r++)
                    LaccW[((r & 3) + 8 * (r >> 2) + hi4) * 128 + nb * 32 + c31] = accO[nb][r];
            if (l < 32) { Lm[w][c31] = mrow; Ll[w][c31] = lsum; }
        }
        __syncthreads();

        {
            const int row = tid >> 4;
            const int c0  = (tid & 15) * 8;
            float mv[8], lv[8];
            #pragma unroll
            for (int p2 = 0; p2 < 8; p2++) { mv[p2] = Lm[p2][row]; lv[p2] = Ll[p2][row]; }
            float ms = mv[0];
            #pragma unroll
            for (int p2 = 1; p2 < 8; p2++) ms = fmaxf(ms, mv[p2]);
            float fv[8];
            float L = 0.f;
            #pragma unroll
            for (int p2 = 0; p2 < 8; p2++) { fv[p2] = exp2f(mv[p2] - ms); L += lv[p2] * fv[p2]; }
            float inv = 1.0f / L;
            float* op = &out[((long)b * T_SEQ + q0 + row) * HS + c0];
            #pragma unroll
            for (int j = 0; j < 8; j++) {
                float o = 0.f;
                #pragma unroll
                for (int p2 = 0; p2 < 8; p2++)
                    o += ((const float*)(pool + (p2 << 14)))[row * 128 + c0 + j] * fv[p2];
                op[j] = o * inv;
            }
        }
        __syncthreads();   // merge reads done before next phase restages K
    }
#undef STAGEK
}

// ---------------- launch ------------------------------------------------------
extern "C" void kernel_launch(void* const* d_in, const int* in_sizes, int n_in,
                              void* d_out, int out_size, void* d_ws, size_t ws_size,
                              hipStream_t stream) {
    const float* x  = (const float*)d_in[0];
    const float* Wk = (const float*)d_in[1];
    const float* Wq = (const float*)d_in[2];
    const float* Wv = (const float*)d_in[3];
    float* out = (float*)d_out;

    char* ws = (char*)d_ws;
    short* Wt  = (short*)ws;                                  // 1.5 MB (swizzled panels)
    short* qg  = (short*)(ws + 1572864);                      // 4 MB
    short* kg  = (short*)(ws + 1572864 + 4194304);            // 4 MB (K tile images)
    short* vtg = (short*)(ws + 1572864 + 8388608);            // 4 MB

    wt_kernel  <<<3072, 256, 0, stream>>>(Wq, Wk, Wv, Wt);
    proj_kernel<<<768,  256, 0, stream>>>(x, Wt, qg, kg, vtg);
    attn_kernel<<<256,  512, 0, stream>>>(qg, kg, vtg, out);
}